// Round 2
// baseline (542.894 us; speedup 1.0000x reference)
//
#include <hip/hip_runtime.h>
#include <hip/hip_bf16.h>
#include <cmath>

// Problem: B=4, S=1024, D_MODEL=1024, H=16, D_SP=512, DEPTH=64
// Inputs f32; outputs f32: out [4,1024,1024] then attn [4,16,1024,1024].

typedef __bf16 bf16x8 __attribute__((ext_vector_type(8)));
typedef __bf16 bf16x4 __attribute__((ext_vector_type(4)));
typedef float  f32x4  __attribute__((ext_vector_type(4)));

#define MFMA16(a, b, c) __builtin_amdgcn_mfma_f32_16x16x32_bf16((a), (b), (c), 0, 0, 0)

static constexpr int S = 1024, DM = 1024, H = 16, DEPTH = 64;

__device__ inline float wave_max(float v) {
#pragma unroll
  for (int o = 32; o > 0; o >>= 1) v = fmaxf(v, __shfl_xor(v, o));
  return v;
}
__device__ inline float wave_sum(float v) {
#pragma unroll
  for (int o = 32; o > 0; o >>= 1) v += __shfl_xor(v, o);
  return v;
}

__device__ inline bf16x8 cvt8(const float* p) {
  float4 f0 = *reinterpret_cast<const float4*>(p);
  float4 f1 = *reinterpret_cast<const float4*>(p + 4);
  bf16x8 a = {(__bf16)f0.x, (__bf16)f0.y, (__bf16)f0.z, (__bf16)f0.w,
              (__bf16)f1.x, (__bf16)f1.y, (__bf16)f1.z, (__bf16)f1.w};
  return a;
}

// ---------------- weight transpose+cast: W [K,N] f32 -> WT [N,K] bf16 ----------------
__global__ __launch_bounds__(256) void transpose_cast(const float* __restrict__ W,
                                                      __bf16* __restrict__ WT, int K, int N) {
  int tid = blockIdx.x * 256 + threadIdx.x;
  int k = tid / N, n = tid - k * N;
  WT[(size_t)n * K + k] = (__bf16)W[tid];
}

// ---------------- generic dense GEMM: C[4096,N] = act(A[4096,K] @ BT^T + bias) ----------------
// AF32: A is f32 (convert in-kernel); else bf16.
// MODE 0: row-major store out[row*N+col]
// MODE 1: head-split store   out[((b*H+h)*S+s)*64+d]
// MODE 2: transposed-v store out[((b*H+h)*64+d)*S+s]
template <int K, bool RELU, int MODE, bool AF32, typename OutT>
__global__ __launch_bounds__(256) void gemm16(const void* __restrict__ Av,
                                              const __bf16* __restrict__ BT,
                                              const float* __restrict__ bias,
                                              OutT* __restrict__ out, int N) {
  int lane = threadIdx.x & 63, wv = threadIdx.x >> 6;
  int row0 = blockIdx.y * 64 + wv * 16;
  int col0 = blockIdx.x * 64;
  int lr = lane & 15, lk = (lane >> 4) * 8;
  f32x4 acc[4] = {};
  for (int k0 = 0; k0 < K; k0 += 32) {
    bf16x8 a;
    if (AF32) {
      a = cvt8((const float*)Av + (size_t)(row0 + lr) * K + k0 + lk);
    } else {
      a = *reinterpret_cast<const bf16x8*>((const __bf16*)Av + (size_t)(row0 + lr) * K + k0 + lk);
    }
#pragma unroll
    for (int t = 0; t < 4; t++) {
      bf16x8 b = *reinterpret_cast<const bf16x8*>(BT + (size_t)(col0 + t * 16 + lr) * K + k0 + lk);
      acc[t] = MFMA16(a, b, acc[t]);
    }
  }
  int rb = (lane >> 4) * 4;
#pragma unroll
  for (int t = 0; t < 4; t++) {
    int col = col0 + t * 16 + lr;
    float bia = bias[col];
#pragma unroll
    for (int r = 0; r < 4; r++) {
      int row = row0 + rb + r;
      float v = acc[t][r] + bia;
      if (RELU) v = fmaxf(v, 0.0f);
      if (MODE == 0) {
        out[(size_t)row * N + col] = (OutT)v;
      } else if (MODE == 1) {
        int bb = row >> 10, s = row & 1023, h = col >> 6, d = col & 63;
        out[(((size_t)(bb * H + h)) * S + s) * DEPTH + d] = (OutT)v;
      } else {
        int bb = row >> 10, s = row & 1023, h = col >> 6, d = col & 63;
        out[(((size_t)(bb * H + h)) * DEPTH + d) * S + s] = (OutT)v;
      }
    }
  }
}

// ---------------- logits + mask + softmax, writes attn (f32) ----------------
// grid: (S/16, B*H); block 256 (4 waves). Each block: 16 q-rows for one (b,h).
__global__ __launch_bounds__(256) void attn_softmax(const __bf16* __restrict__ qh,
                                                    const __bf16* __restrict__ kh,
                                                    const float* __restrict__ mask,
                                                    float* __restrict__ attn) {
  __shared__ float lds[16][1024];
  int lane = threadIdx.x & 63, wv = threadIdx.x >> 6;
  int q0 = blockIdx.x * 16;
  int bh = blockIdx.y;
  int b = bh >> 4;
  int lr = lane & 15, lk = (lane >> 4) * 8;
  const __bf16* qbase = qh + (size_t)bh * S * DEPTH;
  const __bf16* kbase = kh + (size_t)bh * S * DEPTH;
  bf16x8 a0 = *reinterpret_cast<const bf16x8*>(qbase + (q0 + lr) * DEPTH + lk);
  bf16x8 a1 = *reinterpret_cast<const bf16x8*>(qbase + (q0 + lr) * DEPTH + 32 + lk);
  int rb = (lane >> 4) * 4;
  for (int ct = 0; ct < 16; ct++) {
    int col0 = (ct * 4 + wv) * 16;
    f32x4 acc = {};
    bf16x8 b0 = *reinterpret_cast<const bf16x8*>(kbase + (col0 + lr) * DEPTH + lk);
    bf16x8 b1 = *reinterpret_cast<const bf16x8*>(kbase + (col0 + lr) * DEPTH + 32 + lk);
    acc = MFMA16(a0, b0, acc);
    acc = MFMA16(a1, b1, acc);
#pragma unroll
    for (int r = 0; r < 4; r++) {
      int row = rb + r;
      int col = col0 + lr;
      float mv = mask[((size_t)b * S + q0 + row) * S + col];
      lds[row][col] = acc[r] * 0.125f + mv * (-1e9f);
    }
  }
  __syncthreads();
  float* abase = attn + (size_t)bh * S * S + (size_t)q0 * S;
  for (int rr = 0; rr < 4; rr++) {
    int row = wv * 4 + rr;
    float m = -__builtin_inff();
#pragma unroll
    for (int i = 0; i < 16; i++) m = fmaxf(m, lds[row][lane + 64 * i]);
    m = wave_max(m);
    float e[16];
    float ssum = 0.f;
#pragma unroll
    for (int i = 0; i < 16; i++) {
      e[i] = expf(lds[row][lane + 64 * i] - m);
      ssum += e[i];
    }
    ssum = wave_sum(ssum);
    float inv = 1.0f / ssum;
#pragma unroll
    for (int i = 0; i < 16; i++) abase[(size_t)row * S + lane + 64 * i] = e[i] * inv;
  }
}

// ---------------- ctx = attn @ vh -> concat [B,S,H*64] ----------------
// grid: (S/64, B*H); block 256 (4 waves). attn f32 [B,H,S,S]; vhT bf16 [B,H,64,S].
__global__ __launch_bounds__(256) void ctx_gemm(const float* __restrict__ attn,
                                                const __bf16* __restrict__ vhT,
                                                __bf16* __restrict__ concat) {
  int lane = threadIdx.x & 63, wv = threadIdx.x >> 6;
  int bh = blockIdx.y;
  int b = bh >> 4, h = bh & 15;
  int row0 = blockIdx.x * 64 + wv * 16;
  int lr = lane & 15, lk = (lane >> 4) * 8;
  const float* abase = attn + ((size_t)bh << 20);
  const __bf16* vbase = vhT + (size_t)bh * DEPTH * S;
  f32x4 acc[4] = {};
  for (int k0 = 0; k0 < 1024; k0 += 32) {
    bf16x8 a = cvt8(abase + (size_t)(row0 + lr) * S + k0 + lk);
#pragma unroll
    for (int t = 0; t < 4; t++) {
      bf16x8 bb = *reinterpret_cast<const bf16x8*>(vbase + (size_t)(t * 16 + lr) * S + k0 + lk);
      acc[t] = MFMA16(a, bb, acc[t]);
    }
  }
  int rb = (lane >> 4) * 4;
#pragma unroll
  for (int t = 0; t < 4; t++)
#pragma unroll
    for (int r = 0; r < 4; r++) {
      int row = row0 + rb + r, col = t * 16 + lr;
      concat[((size_t)b * S + row) * DM + h * DEPTH + col] = (__bf16)acc[t][r];
    }
}

// ---------------- launch ----------------

extern "C" void kernel_launch(void* const* d_in, const int* in_sizes, int n_in,
                              void* d_out, int out_size, void* d_ws, size_t ws_size,
                              hipStream_t stream) {
  const float* q    = (const float*)d_in[0];
  const float* mdm  = (const float*)d_in[1];
  const float* mask = (const float*)d_in[2];
  const float* W_sp = (const float*)d_in[3];
  const float* b_sp = (const float*)d_in[4];
  const float* Wq   = (const float*)d_in[5];
  const float* bq   = (const float*)d_in[6];
  const float* Wk   = (const float*)d_in[7];
  const float* bk   = (const float*)d_in[8];
  const float* Wv   = (const float*)d_in[9];
  const float* bv   = (const float*)d_in[10];
  const float* Wo   = (const float*)d_in[11];
  const float* bo   = (const float*)d_in[12];

  char* p = (char*)d_ws;
  __bf16* WspT   = (__bf16*)p; p += (size_t)524288 * 2;
  __bf16* WqT    = (__bf16*)p; p += (size_t)1048576 * 2;
  __bf16* WkT    = (__bf16*)p; p += (size_t)524288 * 2;
  __bf16* WvT    = (__bf16*)p; p += (size_t)524288 * 2;
  __bf16* WoT    = (__bf16*)p; p += (size_t)1048576 * 2;
  __bf16* sp     = (__bf16*)p; p += (size_t)2097152 * 2;
  __bf16* qh     = (__bf16*)p; p += (size_t)4194304 * 2;
  __bf16* kh     = (__bf16*)p; p += (size_t)4194304 * 2;
  __bf16* vhT    = (__bf16*)p; p += (size_t)4194304 * 2;
  __bf16* concat = (__bf16*)p; p += (size_t)4194304 * 2;

  float* out_p  = (float*)d_out;
  float* attn_p = (float*)d_out + (size_t)4194304;

  // weight transposes (to [N,K] bf16)
  transpose_cast<<<2048, 256, 0, stream>>>(W_sp, WspT, 1024, 512);
  transpose_cast<<<4096, 256, 0, stream>>>(Wq, WqT, 1024, 1024);
  transpose_cast<<<2048, 256, 0, stream>>>(Wk, WkT, 512, 1024);
  transpose_cast<<<2048, 256, 0, stream>>>(Wv, WvT, 512, 1024);
  transpose_cast<<<4096, 256, 0, stream>>>(Wo, WoT, 1024, 1024);

  // sp = relu(mdm @ W_sp + b_sp)   [4096,512] bf16
  gemm16<1024, true, 0, true, __bf16><<<dim3(8, 64), 256, 0, stream>>>(mdm, WspT, b_sp, sp, 512);
  // qh = split_heads(q @ Wq + bq)  [B,H,S,64] bf16
  gemm16<1024, false, 1, true, __bf16><<<dim3(16, 64), 256, 0, stream>>>(q, WqT, bq, qh, 1024);
  // kh = split_heads(sp @ Wk + bk) [B,H,S,64] bf16
  gemm16<512, false, 1, false, __bf16><<<dim3(16, 64), 256, 0, stream>>>(sp, WkT, bk, kh, 1024);
  // vhT = split_heads(sp @ Wv + bv) transposed -> [B,H,64,S] bf16
  gemm16<512, false, 2, false, __bf16><<<dim3(16, 64), 256, 0, stream>>>(sp, WvT, bv, vhT, 1024);

  // attn = softmax(qh@kh^T * scale + mask*NEG_INF) -> d_out (f32)
  attn_softmax<<<dim3(64, 64), 256, 0, stream>>>(qh, kh, mask, attn_p);
  // ctx = attn @ vh -> concat [4096,1024] bf16
  ctx_gemm<<<dim3(16, 64), 256, 0, stream>>>(attn_p, vhT, concat);
  // out = concat @ Wo + bo -> d_out (f32)
  gemm16<1024, false, 0, false, float><<<dim3(16, 64), 256, 0, stream>>>(concat, WoT, bo, out_p, 1024);
}

// Round 3
// 381.804 us; speedup vs baseline: 1.4219x; 1.4219x over previous
//
#include <hip/hip_runtime.h>
#include <hip/hip_bf16.h>
#include <cmath>

// B=4, S=1024, D_MODEL=1024, H=16, D_SP=512, DEPTH=64
// Inputs f32; outputs f32: out [4,1024,1024] then attn [4,16,1024,1024].

typedef __bf16 bf16x8 __attribute__((ext_vector_type(8)));
typedef __bf16 bf16x4 __attribute__((ext_vector_type(4)));
typedef float  f32x4  __attribute__((ext_vector_type(4)));

#define MFMA16(a, b, c) __builtin_amdgcn_mfma_f32_16x16x32_bf16((a), (b), (c), 0, 0, 0)

static constexpr int S = 1024, DM = 1024, H = 16, DEPTH = 64;

__device__ inline float wave_max(float v) {
#pragma unroll
  for (int o = 32; o > 0; o >>= 1) v = fmaxf(v, __shfl_xor(v, o));
  return v;
}
__device__ inline float wave_sum(float v) {
#pragma unroll
  for (int o = 32; o > 0; o >>= 1) v += __shfl_xor(v, o);
  return v;
}

__device__ inline bf16x8 cvt8(const float* p) {
  float4 f0 = *reinterpret_cast<const float4*>(p);
  float4 f1 = *reinterpret_cast<const float4*>(p + 4);
  bf16x8 a = {(__bf16)f0.x, (__bf16)f0.y, (__bf16)f0.z, (__bf16)f0.w,
              (__bf16)f1.x, (__bf16)f1.y, (__bf16)f1.z, (__bf16)f1.w};
  return a;
}

// ---------------- LDS-tiled transpose+cast: W [K,N] f32 -> WT [N,K] bf16 ----------------
// grid (K/64, N/64), block 256.
__global__ __launch_bounds__(256) void transpose_cast(const float* __restrict__ W,
                                                      __bf16* __restrict__ WT, int K, int N) {
  __shared__ float tile[64][65];
  int k0 = blockIdx.x * 64, n0 = blockIdx.y * 64;
  int t = threadIdx.x;
  int r = t >> 2, c4 = (t & 3) * 16;
  const float* src = W + (size_t)(k0 + r) * N + n0 + c4;
#pragma unroll
  for (int j = 0; j < 4; j++) {
    float4 v = *reinterpret_cast<const float4*>(src + j * 4);
    tile[r][c4 + j * 4 + 0] = v.x;
    tile[r][c4 + j * 4 + 1] = v.y;
    tile[r][c4 + j * 4 + 2] = v.z;
    tile[r][c4 + j * 4 + 3] = v.w;
  }
  __syncthreads();
  // write: row n = r, k-range [c4, c4+16)
  __bf16* dst = WT + (size_t)(n0 + r) * K + k0 + c4;
  bf16x8 o0, o1;
#pragma unroll
  for (int j = 0; j < 8; j++) {
    o0[j] = (__bf16)tile[c4 + j][r];
    o1[j] = (__bf16)tile[c4 + 8 + j][r];
  }
  *reinterpret_cast<bf16x8*>(dst) = o0;
  *reinterpret_cast<bf16x8*>(dst + 8) = o1;
}

// ---------------- dense GEMM: C[4096,N] = act(A[4096,K] @ BT^T + bias) ----------------
// 128 rows x 64 cols per block; 4 waves, 32 rows/wave.
// MODE 0: row-major; MODE 1: head-split [B,H,S,64]; MODE 2: v-transposed [B,H,64,S].
template <int K, bool RELU, int MODE, bool AF32, typename OutT>
__global__ __launch_bounds__(256) void gemm16(const void* __restrict__ Av,
                                              const __bf16* __restrict__ BT,
                                              const float* __restrict__ bias,
                                              OutT* __restrict__ out, int N) {
  int lane = threadIdx.x & 63, wv = threadIdx.x >> 6;
  int row0 = blockIdx.y * 128 + wv * 32;
  int col0 = blockIdx.x * 64;
  int lr = lane & 15, lk = (lane >> 4) * 8;
  f32x4 acc[2][4] = {};
  for (int k0 = 0; k0 < K; k0 += 32) {
    bf16x8 a0, a1;
    if (AF32) {
      a0 = cvt8((const float*)Av + (size_t)(row0 + lr) * K + k0 + lk);
      a1 = cvt8((const float*)Av + (size_t)(row0 + 16 + lr) * K + k0 + lk);
    } else {
      a0 = *reinterpret_cast<const bf16x8*>((const __bf16*)Av + (size_t)(row0 + lr) * K + k0 + lk);
      a1 = *reinterpret_cast<const bf16x8*>((const __bf16*)Av + (size_t)(row0 + 16 + lr) * K + k0 + lk);
    }
#pragma unroll
    for (int t = 0; t < 4; t++) {
      bf16x8 b = *reinterpret_cast<const bf16x8*>(BT + (size_t)(col0 + t * 16 + lr) * K + k0 + lk);
      acc[0][t] = MFMA16(a0, b, acc[0][t]);
      acc[1][t] = MFMA16(a1, b, acc[1][t]);
    }
  }
  int rb = (lane >> 4) * 4;
#pragma unroll
  for (int half = 0; half < 2; half++)
#pragma unroll
    for (int t = 0; t < 4; t++) {
      int col = col0 + t * 16 + lr;
      float bia = bias[col];
#pragma unroll
      for (int r = 0; r < 4; r++) {
        int row = row0 + half * 16 + rb + r;
        float v = acc[half][t][r] + bia;
        if (RELU) v = fmaxf(v, 0.0f);
        if (MODE == 0) {
          out[(size_t)row * N + col] = (OutT)v;
        } else if (MODE == 1) {
          int bb = row >> 10, s = row & 1023, h = col >> 6, d = col & 63;
          out[(((size_t)(bb * H + h)) * S + s) * DEPTH + d] = (OutT)v;
        } else {
          int bb = row >> 10, s = row & 1023, h = col >> 6, d = col & 63;
          out[(((size_t)(bb * H + h)) * DEPTH + d) * S + s] = (OutT)v;
        }
      }
    }
}

// ---------------- fused logits + mask + softmax + PV ----------------
// grid: (S/16, B*H); block 256 (4 waves). 16 q-rows per block.
// Writes attn f32 (d_out) and ctx -> concat bf16 [B,S,H*64].
// LDS: s_lds[16][1024] f32 (logits). P bf16 overwrites row prefix in-place
// (XOR-swizzled); PV partials go in the freed row tail (words [512,768)).
__global__ __launch_bounds__(256) void attn_fused(const __bf16* __restrict__ qh,
                                                  const __bf16* __restrict__ kh,
                                                  const __bf16* __restrict__ vhT,
                                                  const float* __restrict__ mask,
                                                  float* __restrict__ attn,
                                                  __bf16* __restrict__ concat) {
  __shared__ float s_lds[16][1024];
  float* flat = &s_lds[0][0];
  int lane = threadIdx.x & 63, wv = threadIdx.x >> 6;
  int q0 = blockIdx.x * 16;
  int bh = blockIdx.y;
  int b = bh >> 4, h = bh & 15;
  int lr = lane & 15, lk = (lane >> 4) * 8;
  int hi = lane >> 4;

  const __bf16* qbase = qh + (size_t)bh * S * DEPTH;
  const __bf16* kbase = kh + (size_t)bh * S * DEPTH;
  const __bf16* vbase = vhT + (size_t)bh * DEPTH * S;

  // ---- QK^T -> logits in LDS ----
  bf16x8 a0 = *reinterpret_cast<const bf16x8*>(qbase + (q0 + lr) * DEPTH + lk);
  bf16x8 a1 = *reinterpret_cast<const bf16x8*>(qbase + (q0 + lr) * DEPTH + 32 + lk);
  int rb = hi * 4;
  for (int ct = 0; ct < 16; ct++) {
    int col0 = (ct * 4 + wv) * 16;
    f32x4 acc = {};
    bf16x8 b0 = *reinterpret_cast<const bf16x8*>(kbase + (col0 + lr) * DEPTH + lk);
    bf16x8 b1 = *reinterpret_cast<const bf16x8*>(kbase + (col0 + lr) * DEPTH + 32 + lk);
    acc = MFMA16(a0, b0, acc);
    acc = MFMA16(a1, b1, acc);
#pragma unroll
    for (int r = 0; r < 4; r++) {
      int row = rb + r;
      int col = col0 + lr;
      float mv = mask[((size_t)b * S + q0 + row) * S + col];
      s_lds[row][col] = acc[r] * 0.125f + mv * (-1e9f);
    }
  }
  __syncthreads();

  // ---- softmax (wave w owns rows 4w..4w+3); write attn f32 + P bf16 (in-place, swizzled) ----
  float* abase = attn + (size_t)bh * S * S + (size_t)q0 * S;
  for (int rr = 0; rr < 4; rr++) {
    int row = wv * 4 + rr;
    float v[16];
#pragma unroll
    for (int i = 0; i < 16; i++) v[i] = s_lds[row][lane + 64 * i];
    float m = -__builtin_inff();
#pragma unroll
    for (int i = 0; i < 16; i++) m = fmaxf(m, v[i]);
    m = wave_max(m);
    float e[16];
    float ssum = 0.f;
#pragma unroll
    for (int i = 0; i < 16; i++) {
      e[i] = expf(v[i] - m);
      ssum += e[i];
    }
    ssum = wave_sum(ssum);
    float inv = 1.0f / ssum;
    char* prow = (char*)flat + row * 4096;
#pragma unroll
    for (int i = 0; i < 16; i++) {
      float p = e[i] * inv;
      int col = lane + 64 * i;
      abase[(size_t)row * S + col] = p;
      int byte = (col * 2) ^ ((row & 7) << 4);
      *(__bf16*)(prow + byte) = (__bf16)p;
    }
  }
  __syncthreads();

  // ---- PV: wave w takes K-chunk [256w, 256w+256); out tile 16x64 ----
  f32x4 pacc[4] = {};
  int kw = wv * 256;
#pragma unroll
  for (int step = 0; step < 8; step++) {
    int k0 = kw + step * 32;
    int byte = lr * 4096 + ((k0 + hi * 8) * 2 ^ ((lr & 7) << 4));
    bf16x8 a = *(const bf16x8*)((const char*)flat + byte);
#pragma unroll
    for (int t = 0; t < 4; t++) {
      bf16x8 bb = *reinterpret_cast<const bf16x8*>(vbase + (size_t)(t * 16 + lr) * S + k0 + lk);
      pacc[t] = MFMA16(a, bb, pacc[t]);
    }
  }
  // write partials to freed LDS tail: flat[row*1024 + 512 + wv*64 + col]
#pragma unroll
  for (int t = 0; t < 4; t++)
#pragma unroll
    for (int r = 0; r < 4; r++) {
      int row = rb + r;
      flat[row * 1024 + 512 + wv * 64 + t * 16 + lr] = pacc[t][r];
    }
  __syncthreads();

  // ---- cross-wave reduce + store ctx to concat ----
  int row = threadIdx.x >> 4;
  int c0 = (threadIdx.x & 15) * 4;
  f32x4 sum = {};
#pragma unroll
  for (int w = 0; w < 4; w++) sum += *reinterpret_cast<f32x4*>(&flat[row * 1024 + 512 + w * 64 + c0]);
  __bf16* cdst = concat + ((size_t)b * S + q0 + row) * DM + h * DEPTH + c0;
  bf16x4 o = {(__bf16)sum[0], (__bf16)sum[1], (__bf16)sum[2], (__bf16)sum[3]};
  *reinterpret_cast<bf16x4*>(cdst) = o;
}

// ---------------- launch ----------------

extern "C" void kernel_launch(void* const* d_in, const int* in_sizes, int n_in,
                              void* d_out, int out_size, void* d_ws, size_t ws_size,
                              hipStream_t stream) {
  const float* q    = (const float*)d_in[0];
  const float* mdm  = (const float*)d_in[1];
  const float* mask = (const float*)d_in[2];
  const float* W_sp = (const float*)d_in[3];
  const float* b_sp = (const float*)d_in[4];
  const float* Wq   = (const float*)d_in[5];
  const float* bq   = (const float*)d_in[6];
  const float* Wk   = (const float*)d_in[7];
  const float* bk   = (const float*)d_in[8];
  const float* Wv   = (const float*)d_in[9];
  const float* bv   = (const float*)d_in[10];
  const float* Wo   = (const float*)d_in[11];
  const float* bo   = (const float*)d_in[12];

  char* p = (char*)d_ws;
  __bf16* WspT   = (__bf16*)p; p += (size_t)524288 * 2;
  __bf16* WqT    = (__bf16*)p; p += (size_t)1048576 * 2;
  __bf16* WkT    = (__bf16*)p; p += (size_t)524288 * 2;
  __bf16* WvT    = (__bf16*)p; p += (size_t)524288 * 2;
  __bf16* WoT    = (__bf16*)p; p += (size_t)1048576 * 2;
  __bf16* sp     = (__bf16*)p; p += (size_t)2097152 * 2;
  __bf16* qh     = (__bf16*)p; p += (size_t)4194304 * 2;
  __bf16* kh     = (__bf16*)p; p += (size_t)4194304 * 2;
  __bf16* vhT    = (__bf16*)p; p += (size_t)4194304 * 2;
  __bf16* concat = (__bf16*)p; p += (size_t)4194304 * 2;

  float* out_p  = (float*)d_out;
  float* attn_p = (float*)d_out + (size_t)4194304;

  // weight transposes (to [N,K] bf16), LDS-tiled
  transpose_cast<<<dim3(16, 8), 256, 0, stream>>>(W_sp, WspT, 1024, 512);
  transpose_cast<<<dim3(16, 16), 256, 0, stream>>>(Wq, WqT, 1024, 1024);
  transpose_cast<<<dim3(8, 16), 256, 0, stream>>>(Wk, WkT, 512, 1024);
  transpose_cast<<<dim3(8, 16), 256, 0, stream>>>(Wv, WvT, 512, 1024);
  transpose_cast<<<dim3(16, 16), 256, 0, stream>>>(Wo, WoT, 1024, 1024);

  // sp = relu(mdm @ W_sp + b_sp)   [4096,512] bf16
  gemm16<1024, true, 0, true, __bf16><<<dim3(8, 32), 256, 0, stream>>>(mdm, WspT, b_sp, sp, 512);
  // qh = split_heads(q @ Wq + bq)  [B,H,S,64] bf16
  gemm16<1024, false, 1, true, __bf16><<<dim3(16, 32), 256, 0, stream>>>(q, WqT, bq, qh, 1024);
  // kh = split_heads(sp @ Wk + bk) [B,H,S,64] bf16
  gemm16<512, false, 1, false, __bf16><<<dim3(16, 32), 256, 0, stream>>>(sp, WkT, bk, kh, 1024);
  // vhT = split_heads(sp @ Wv + bv) transposed -> [B,H,64,S] bf16
  gemm16<512, false, 2, false, __bf16><<<dim3(16, 32), 256, 0, stream>>>(sp, WvT, bv, vhT, 1024);

  // fused: attn (f32, d_out) + ctx -> concat
  attn_fused<<<dim3(64, 64), 256, 0, stream>>>(qh, kh, vhT, mask, attn_p, concat);

  // out = concat @ Wo + bo -> d_out (f32)
  gemm16<1024, false, 0, false, float><<<dim3(16, 32), 256, 0, stream>>>(concat, WoT, bo, out_p, 1024);
}